// Round 11
// baseline (406.477 us; speedup 1.0000x reference)
//
#include <hip/hip_runtime.h>
#include <hip/hip_bf16.h>
#include <math.h>

#define N_NODES 50000

typedef short short8 __attribute__((ext_vector_type(8)));
typedef float f32x4 __attribute__((ext_vector_type(4)));

// RNE split of f32 into bf16 hi + bf16 lo (a ~= hi + lo, rel err ~2^-18)
static __device__ __forceinline__ void split2(float x, unsigned short& hi, unsigned short& lo) {
    unsigned u = __builtin_bit_cast(unsigned, x);
    unsigned r = u + 0x7FFF + ((u >> 16) & 1);
    hi = (unsigned short)(r >> 16);
    float hf = __builtin_bit_cast(float, (unsigned)hi << 16);
    float res = x - hf;
    unsigned v = __builtin_bit_cast(unsigned, res);
    unsigned r2 = v + 0x7FFF + ((v >> 16) & 1);
    lo = (unsigned short)(r2 >> 16);
}

// ---------------- degree (int histogram) ----------------

__global__ void deg_kernel(const int* __restrict__ dst, int* __restrict__ deg, int E) {
    int e = blockIdx.x * blockDim.x + threadIdx.x;
    if (e < E) atomicAdd(&deg[dst[e]], 1);
}

// ---------------- multi-block exclusive scan ----------------

__global__ void scan_p1(const int* __restrict__ deg, int* __restrict__ bsum, int n) {
    int t = threadIdx.x;                    // 256 threads
    int base = blockIdx.x * 1024 + t * 4;
    int4 v = make_int4(0, 0, 0, 0);
    if (base + 3 < n) v = *(const int4*)(deg + base);
    else {
        if (base + 0 < n) v.x = deg[base + 0];
        if (base + 1 < n) v.y = deg[base + 1];
        if (base + 2 < n) v.z = deg[base + 2];
    }
    int s = v.x + v.y + v.z + v.w;
    #pragma unroll
    for (int off = 32; off > 0; off >>= 1) s += __shfl_xor(s, off);
    __shared__ int wpart[4];
    if ((t & 63) == 0) wpart[t >> 6] = s;
    __syncthreads();
    if (t == 0) bsum[blockIdx.x] = wpart[0] + wpart[1] + wpart[2] + wpart[3];
}

__global__ void scan_p2(int* __restrict__ bsum, int nb, int* __restrict__ rowptr, int n) {
    int t = threadIdx.x;                    // 64 threads, nb <= 64
    int v = (t < nb) ? bsum[t] : 0;
    int sc = v;
    #pragma unroll
    for (int off = 1; off < 64; off <<= 1) {
        int u = __shfl_up(sc, off);
        if (t >= off) sc += u;
    }
    if (t < nb) bsum[t] = sc - v;           // exclusive block offsets
    if (t == 63) rowptr[n] = sc;            // grand total
}

// scan_p3 also computes inv_sqrt(deg) (folded kernel)
__global__ void scan_p3(const int* __restrict__ deg, const int* __restrict__ bsum,
                        int* __restrict__ rowptr, int* __restrict__ cursor,
                        float* __restrict__ inv, int n) {
    int t = threadIdx.x;                    // 256 threads
    int base = blockIdx.x * 1024 + t * 4;
    int4 v = make_int4(0, 0, 0, 0);
    if (base + 3 < n) v = *(const int4*)(deg + base);
    else {
        if (base + 0 < n) v.x = deg[base + 0];
        if (base + 1 < n) v.y = deg[base + 1];
        if (base + 2 < n) v.z = deg[base + 2];
    }
    int s = v.x + v.y + v.z + v.w;
    int lane = t & 63;
    int sc = s;
    #pragma unroll
    for (int off = 1; off < 64; off <<= 1) {
        int u = __shfl_up(sc, off);
        if (lane >= off) sc += u;
    }
    __shared__ int wpart[4], woff[4];
    if (lane == 63) wpart[t >> 6] = sc;
    __syncthreads();
    if (t == 0) { int a = 0; for (int i = 0; i < 4; ++i) { woff[i] = a; a += wpart[i]; } }
    __syncthreads();
    int run = bsum[blockIdx.x] + woff[t >> 6] + (sc - s);
    if (base + 0 < n) { rowptr[base + 0] = run; cursor[base + 0] = run; run += v.x; inv[base + 0] = rsqrtf(fmaxf((float)v.x, 1.0f)); }
    if (base + 1 < n) { rowptr[base + 1] = run; cursor[base + 1] = run; run += v.y; inv[base + 1] = rsqrtf(fmaxf((float)v.y, 1.0f)); }
    if (base + 2 < n) { rowptr[base + 2] = run; cursor[base + 2] = run; run += v.z; inv[base + 2] = rsqrtf(fmaxf((float)v.z, 1.0f)); }
    if (base + 3 < n) { rowptr[base + 3] = run; cursor[base + 3] = run; run += v.w; inv[base + 3] = rsqrtf(fmaxf((float)v.w, 1.0f)); }
}

// ---------------- bucket edges by dst (counting sort fill) ----------------

__global__ void fill_kernel(const int* __restrict__ src, const int* __restrict__ dst,
                            const float* __restrict__ inv, int* __restrict__ cursor,
                            int* __restrict__ src_s, float* __restrict__ norm_s, int E) {
    int e = blockIdx.x * blockDim.x + threadIdx.x;
    if (e >= E) return;
    int s = src[e];
    int d = dst[e];
    int pos = atomicAdd(&cursor[d], 1);
    src_s[pos] = s;
    norm_s[pos] = inv[s] * inv[d];
}

// ---------------- W split + transpose (both weights in one launch) ----------------

__global__ void split_w_all(const float* __restrict__ W1, const float* __restrict__ W2,
                            unsigned short* __restrict__ w1hi, unsigned short* __restrict__ w1lo,
                            unsigned short* __restrict__ w2hi, unsigned short* __restrict__ w2lo) {
    int i = blockIdx.x * 256 + threadIdx.x;
    if (i < 128 * 256) {
        int k = i >> 8;
        int n = i & 255;
        unsigned short h, l;
        split2(W1[i], h, l);
        w1hi[(size_t)n * 128 + k] = h;
        w1lo[(size_t)n * 128 + k] = l;
    } else {
        int j = i - 128 * 256;
        int k = j >> 8;
        int n = j & 255;
        unsigned short h, l;
        split2(W2[j], h, l);
        w2hi[(size_t)n * 256 + k] = h;
        w2lo[(size_t)n * 256 + k] = l;
    }
}

// ---------------- FUSED gather + MFMA GEMM + bias + ReLU ----------------
// out[M,256] = relu( (S @ X)[M,K] @ W[K,256] + b ), S = normalized adjacency (CSR).
// Block: 256 thr = 4 waves; block owns 32 output rows.
// Phase 1: wave w gathers nodes row0+w*8 .. +8: f32 accumulate over edges
//          (lane covers K cols via float2/float4), split2 -> LDS (chunked, padded).
// Phase 2: swapped-operand split-bf16 MFMA (round-10 proven mapping):
//          acc[cf][rf] = mfma(Wfrag, Afrag); lane stores out[row0+rf*16+(lane&15)]
//          [wave*64+cf*16+(lane>>4)*4 + 0..3] as float4.
// LDS chunk layout [NT][32*40+8]: reads = round-9 pattern (measured ~free);
// chunk pad 8 skews write banks.

template<int K, bool RELU>
__global__ __launch_bounds__(256) void fused_conv_kernel(
    const float* __restrict__ X,
    const int* __restrict__ rowptr, const int* __restrict__ src_s,
    const float* __restrict__ norm_s,
    const unsigned short* __restrict__ Whi, const unsigned short* __restrict__ Wlo,
    const float* __restrict__ bias, float* __restrict__ out, int M)
{
    constexpr int NT = K / 32;
    constexpr int CH = 32 * 40 + 8;         // padded chunk (elements)
    __shared__ unsigned short AsH[NT][CH];
    __shared__ unsigned short AsL[NT][CH];

    int tid = threadIdx.x;
    int lane = tid & 63;
    int wave = tid >> 6;
    int row0 = blockIdx.x * 32;

    // ---- phase 1: gather 8 nodes per wave ----
    for (int i = 0; i < 8; ++i) {
        int r = wave * 8 + i;
        int node = row0 + r;
        if (node >= M) break;               // wave-uniform
        int beg = rowptr[node], end = rowptr[node + 1];

        if constexpr (K == 128) {
            const float* xb = X + (size_t)lane * 2;
            float2 acc = {0.f, 0.f};
            int p = beg;
            for (; p + 2 <= end; p += 2) {
                int s0 = src_s[p], s1 = src_s[p + 1];
                float n0 = norm_s[p], n1 = norm_s[p + 1];
                float2 v0 = *(const float2*)(xb + (size_t)s0 * K);
                float2 v1 = *(const float2*)(xb + (size_t)s1 * K);
                acc.x = fmaf(v0.x, n0, acc.x); acc.y = fmaf(v0.y, n0, acc.y);
                acc.x = fmaf(v1.x, n1, acc.x); acc.y = fmaf(v1.y, n1, acc.y);
            }
            if (p < end) {
                int s0 = src_s[p];
                float n0 = norm_s[p];
                float2 v0 = *(const float2*)(xb + (size_t)s0 * K);
                acc.x = fmaf(v0.x, n0, acc.x); acc.y = fmaf(v0.y, n0, acc.y);
            }
            unsigned short h0, l0, h1, l1;
            split2(acc.x, h0, l0);
            split2(acc.y, h1, l1);
            int c = lane >> 4;                       // chunk = (lane*2)/32
            int e = r * 40 + ((lane & 15) << 1);     // within-chunk k offset
            *(ushort2*)&AsH[c][e] = make_ushort2(h0, h1);
            *(ushort2*)&AsL[c][e] = make_ushort2(l0, l1);
        } else {
            const float* xb = X + (size_t)lane * 4;
            float4 acc = {0.f, 0.f, 0.f, 0.f};
            int p = beg;
            for (; p + 2 <= end; p += 2) {
                int s0 = src_s[p], s1 = src_s[p + 1];
                float n0 = norm_s[p], n1 = norm_s[p + 1];
                float4 v0 = *(const float4*)(xb + (size_t)s0 * K);
                float4 v1 = *(const float4*)(xb + (size_t)s1 * K);
                acc.x = fmaf(v0.x, n0, acc.x); acc.y = fmaf(v0.y, n0, acc.y);
                acc.z = fmaf(v0.z, n0, acc.z); acc.w = fmaf(v0.w, n0, acc.w);
                acc.x = fmaf(v1.x, n1, acc.x); acc.y = fmaf(v1.y, n1, acc.y);
                acc.z = fmaf(v1.z, n1, acc.z); acc.w = fmaf(v1.w, n1, acc.w);
            }
            if (p < end) {
                int s0 = src_s[p];
                float n0 = norm_s[p];
                float4 v0 = *(const float4*)(xb + (size_t)s0 * K);
                acc.x = fmaf(v0.x, n0, acc.x); acc.y = fmaf(v0.y, n0, acc.y);
                acc.z = fmaf(v0.z, n0, acc.z); acc.w = fmaf(v0.w, n0, acc.w);
            }
            unsigned short h0, l0, h1, l1, h2, l2, h3, l3;
            split2(acc.x, h0, l0);
            split2(acc.y, h1, l1);
            split2(acc.z, h2, l2);
            split2(acc.w, h3, l3);
            int c = lane >> 3;                       // chunk = (lane*4)/32
            int e = r * 40 + ((lane & 7) << 2);
            *(ushort4*)&AsH[c][e] = make_ushort4(h0, h1, h2, h3);
            *(ushort4*)&AsL[c][e] = make_ushort4(l0, l1, l2, l3);
        }
    }
    __syncthreads();

    // ---- phase 2: GEMM 32 x 256 from LDS A x global W ----
    int col0 = wave * 64;
    int lr = lane & 15;
    int lhi = lane >> 4;
    int koff0 = lhi * 8;

    f32x4 acc[4][2];
    #pragma unroll
    for (int i = 0; i < 4; ++i)
        #pragma unroll
        for (int j = 0; j < 2; ++j) acc[i][j] = (f32x4){0.f, 0.f, 0.f, 0.f};

    #pragma unroll 2
    for (int t = 0; t < NT; ++t) {
        int ko = t * 32 + koff0;
        short8 bh[4], bl[4];
        #pragma unroll
        for (int cf = 0; cf < 4; ++cf) {
            size_t boff = (size_t)(col0 + cf * 16 + lr) * K + ko;
            bh[cf] = *(const short8*)(Whi + boff);
            bl[cf] = *(const short8*)(Wlo + boff);
        }
        short8 ah[2], al[2];
        #pragma unroll
        for (int rf = 0; rf < 2; ++rf) {
            int e = (rf * 16 + lr) * 40 + koff0;
            ah[rf] = *(const short8*)&AsH[t][e];
            al[rf] = *(const short8*)&AsL[t][e];
        }
        #pragma unroll
        for (int cf = 0; cf < 4; ++cf)
            #pragma unroll
            for (int rf = 0; rf < 2; ++rf) {
                acc[cf][rf] = __builtin_amdgcn_mfma_f32_16x16x32_bf16(bh[cf], ah[rf], acc[cf][rf], 0, 0, 0);
                acc[cf][rf] = __builtin_amdgcn_mfma_f32_16x16x32_bf16(bl[cf], ah[rf], acc[cf][rf], 0, 0, 0);
                acc[cf][rf] = __builtin_amdgcn_mfma_f32_16x16x32_bf16(bh[cf], al[rf], acc[cf][rf], 0, 0, 0);
            }
    }

    // epilogue: bias + relu, float4 stores
    #pragma unroll
    for (int cf = 0; cf < 4; ++cf) {
        int c = col0 + cf * 16 + lhi * 4;
        float4 bv = *(const float4*)(bias + c);
        #pragma unroll
        for (int rf = 0; rf < 2; ++rf) {
            int r = row0 + rf * 16 + lr;
            if (r < M) {
                float4 v;
                v.x = acc[cf][rf][0] + bv.x;
                v.y = acc[cf][rf][1] + bv.y;
                v.z = acc[cf][rf][2] + bv.z;
                v.w = acc[cf][rf][3] + bv.w;
                if (RELU) {
                    v.x = fmaxf(v.x, 0.f); v.y = fmaxf(v.y, 0.f);
                    v.z = fmaxf(v.z, 0.f); v.w = fmaxf(v.w, 0.f);
                }
                *(float4*)(out + (size_t)r * 256 + c) = v;
            }
        }
    }
}

// ---------------- dense head + softmax, LDS-staged ----------------

__global__ __launch_bounds__(256) void dense_softmax_kernel(const float* __restrict__ h,
                                                            const float* __restrict__ Wd,
                                                            const float* __restrict__ bd,
                                                            float* __restrict__ out, int M) {
    __shared__ float hs[32][260];
    __shared__ float wt[40][260];
    int tid = threadIdx.x;
    int row0 = blockIdx.x * 32;

    for (int i = tid; i < 40 * 256; i += 256) {
        int k = i / 40;
        int c = i - k * 40;
        wt[c][k] = Wd[i];
    }
    #pragma unroll
    for (int i = 0; i < 8; ++i) {
        int f = tid + i * 256;
        int r = f >> 6;
        int k4 = (f & 63) << 2;
        float4 v = make_float4(0.f, 0.f, 0.f, 0.f);
        if (row0 + r < M) v = *(const float4*)(h + (size_t)(row0 + r) * 256 + k4);
        *(float4*)&hs[r][k4] = v;
    }
    __syncthreads();

    int r  = tid >> 3;
    int cg = tid & 7;
    int c0 = cg * 5;

    float acc[5] = {0.f, 0.f, 0.f, 0.f, 0.f};
    #pragma unroll 4
    for (int k4 = 0; k4 < 64; ++k4) {
        float4 hv = *(float4*)&hs[r][k4 * 4];
        #pragma unroll
        for (int j = 0; j < 5; ++j) {
            float4 wv = *(float4*)&wt[c0 + j][k4 * 4];
            acc[j] = fmaf(hv.x, wv.x, acc[j]);
            acc[j] = fmaf(hv.y, wv.y, acc[j]);
            acc[j] = fmaf(hv.z, wv.z, acc[j]);
            acc[j] = fmaf(hv.w, wv.w, acc[j]);
        }
    }
    #pragma unroll
    for (int j = 0; j < 5; ++j) acc[j] += bd[c0 + j];

    float m = acc[0];
    #pragma unroll
    for (int j = 1; j < 5; ++j) m = fmaxf(m, acc[j]);
    #pragma unroll
    for (int off = 1; off < 8; off <<= 1) m = fmaxf(m, __shfl_xor(m, off));

    float e[5], s = 0.f;
    #pragma unroll
    for (int j = 0; j < 5; ++j) { e[j] = expf(acc[j] - m); s += e[j]; }
    #pragma unroll
    for (int off = 1; off < 8; off <<= 1) s += __shfl_xor(s, off);

    int row = row0 + r;
    if (row < M) {
        float inv_s = 1.0f / s;
        float* orow = out + (size_t)row * 40 + c0;
        #pragma unroll
        for (int j = 0; j < 5; ++j) orow[j] = e[j] * inv_s;
    }
}

// ---------------- launch ----------------

extern "C" void kernel_launch(void* const* d_in, const int* in_sizes, int n_in,
                              void* d_out, int out_size, void* d_ws, size_t ws_size,
                              hipStream_t stream) {
    const float* x  = (const float*)d_in[0];
    const int*   ei = (const int*)d_in[1];
    const float* W1 = (const float*)d_in[2];
    const float* b1 = (const float*)d_in[3];
    const float* W2 = (const float*)d_in[4];
    const float* b2 = (const float*)d_in[5];
    const float* Wd = (const float*)d_in[6];
    const float* bd = (const float*)d_in[7];
    float* out = (float*)d_out;

    const int N = N_NODES;
    const int E = in_sizes[1] / 2;
    const int* src = ei;
    const int* dst = ei + E;

    // workspace layout (bytes, 1KB-aligned). ~113 MB.
    char* ws = (char*)d_ws;
    size_t off = 0;
    auto alloc = [&](size_t bytes) { char* p = ws + off; off += (bytes + 1023) & ~(size_t)1023; return p; };
    int*   deg    = (int*)alloc((size_t)N * 4);
    float* inv    = (float*)alloc((size_t)N * 4);
    int*   rowptr = (int*)alloc((size_t)(N + 1) * 4);
    int*   cursor = (int*)alloc((size_t)N * 4);
    int*   bsum   = (int*)alloc((size_t)64 * 4);
    int*   src_s  = (int*)alloc((size_t)E * 4);
    float* norm_s = (float*)alloc((size_t)E * 4);
    float* h1     = (float*)alloc((size_t)N * 256 * 4);
    float* h2     = (float*)alloc((size_t)N * 256 * 4);   // distinct: fused conv2 reads h1 while writing h2
    unsigned short* w1hi = (unsigned short*)alloc((size_t)128 * 256 * 2);
    unsigned short* w1lo = (unsigned short*)alloc((size_t)128 * 256 * 2);
    unsigned short* w2hi = (unsigned short*)alloc((size_t)256 * 256 * 2);
    unsigned short* w2lo = (unsigned short*)alloc((size_t)256 * 256 * 2);

    hipMemsetAsync(deg, 0, (size_t)N * 4, stream);

    const int nb = (N + 1023) / 1024;   // 49 scan blocks

    // degree -> scan (rowptr+cursor+inv) -> bucketed (src_s, norm_s)
    deg_kernel<<<(E + 255) / 256, 256, 0, stream>>>(dst, deg, E);
    scan_p1<<<nb, 256, 0, stream>>>(deg, bsum, N);
    scan_p2<<<1, 64, 0, stream>>>(bsum, nb, rowptr, N);
    scan_p3<<<nb, 256, 0, stream>>>(deg, bsum, rowptr, cursor, inv, N);
    fill_kernel<<<(E + 255) / 256, 256, 0, stream>>>(src, dst, inv, cursor, src_s, norm_s, E);

    // pre-split weights (transposed), one launch
    split_w_all<<<(128 * 256 + 256 * 256) / 256, 256, 0, stream>>>(W1, W2, w1hi, w1lo, w2hi, w2lo);

    const int cblocks = (N + 31) / 32;  // 1563

    // conv1 fused: h1 = relu((S x) @ W1 + b1)
    fused_conv_kernel<128, true><<<cblocks, 256, 0, stream>>>(
        x, rowptr, src_s, norm_s, w1hi, w1lo, b1, h1, N);

    // conv2 fused: h2 = relu((S h1) @ W2 + b2)
    fused_conv_kernel<256, true><<<cblocks, 256, 0, stream>>>(
        h1, rowptr, src_s, norm_s, w2hi, w2lo, b2, h2, N);

    // dense + softmax (LDS-staged)
    dense_softmax_kernel<<<(N + 31) / 32, 256, 0, stream>>>(h2, Wd, bd, out, N);
}

// Round 12
// 363.457 us; speedup vs baseline: 1.1184x; 1.1184x over previous
//
#include <hip/hip_runtime.h>
#include <hip/hip_bf16.h>
#include <math.h>

#define N_NODES 50000

typedef short short8 __attribute__((ext_vector_type(8)));
typedef float f32x4 __attribute__((ext_vector_type(4)));

// RNE split of f32 into bf16 hi + bf16 lo (a ~= hi + lo, rel err ~2^-18)
static __device__ __forceinline__ void split2(float x, unsigned short& hi, unsigned short& lo) {
    unsigned u = __builtin_bit_cast(unsigned, x);
    unsigned r = u + 0x7FFF + ((u >> 16) & 1);
    hi = (unsigned short)(r >> 16);
    float hf = __builtin_bit_cast(float, (unsigned)hi << 16);
    float res = x - hf;
    unsigned v = __builtin_bit_cast(unsigned, res);
    unsigned r2 = v + 0x7FFF + ((v >> 16) & 1);
    lo = (unsigned short)(r2 >> 16);
}

// ---------------- degree (int histogram) ----------------

__global__ void deg_kernel(const int* __restrict__ dst, int* __restrict__ deg, int E) {
    int e = blockIdx.x * blockDim.x + threadIdx.x;
    if (e < E) atomicAdd(&deg[dst[e]], 1);
}

// ---------------- multi-block exclusive scan ----------------

__global__ void scan_p1(const int* __restrict__ deg, int* __restrict__ bsum, int n) {
    int t = threadIdx.x;                    // 256 threads
    int base = blockIdx.x * 1024 + t * 4;
    int4 v = make_int4(0, 0, 0, 0);
    if (base + 3 < n) v = *(const int4*)(deg + base);
    else {
        if (base + 0 < n) v.x = deg[base + 0];
        if (base + 1 < n) v.y = deg[base + 1];
        if (base + 2 < n) v.z = deg[base + 2];
    }
    int s = v.x + v.y + v.z + v.w;
    #pragma unroll
    for (int off = 32; off > 0; off >>= 1) s += __shfl_xor(s, off);
    __shared__ int wpart[4];
    if ((t & 63) == 0) wpart[t >> 6] = s;
    __syncthreads();
    if (t == 0) bsum[blockIdx.x] = wpart[0] + wpart[1] + wpart[2] + wpart[3];
}

__global__ void scan_p2(int* __restrict__ bsum, int nb, int* __restrict__ rowptr, int n) {
    int t = threadIdx.x;                    // 64 threads, nb <= 64
    int v = (t < nb) ? bsum[t] : 0;
    int sc = v;
    #pragma unroll
    for (int off = 1; off < 64; off <<= 1) {
        int u = __shfl_up(sc, off);
        if (t >= off) sc += u;
    }
    if (t < nb) bsum[t] = sc - v;           // exclusive block offsets
    if (t == 63) rowptr[n] = sc;            // grand total
}

// scan_p3 also computes inv_sqrt(deg) (folded kernel)
__global__ void scan_p3(const int* __restrict__ deg, const int* __restrict__ bsum,
                        int* __restrict__ rowptr, int* __restrict__ cursor,
                        float* __restrict__ inv, int n) {
    int t = threadIdx.x;                    // 256 threads
    int base = blockIdx.x * 1024 + t * 4;
    int4 v = make_int4(0, 0, 0, 0);
    if (base + 3 < n) v = *(const int4*)(deg + base);
    else {
        if (base + 0 < n) v.x = deg[base + 0];
        if (base + 1 < n) v.y = deg[base + 1];
        if (base + 2 < n) v.z = deg[base + 2];
    }
    int s = v.x + v.y + v.z + v.w;
    int lane = t & 63;
    int sc = s;
    #pragma unroll
    for (int off = 1; off < 64; off <<= 1) {
        int u = __shfl_up(sc, off);
        if (lane >= off) sc += u;
    }
    __shared__ int wpart[4], woff[4];
    if (lane == 63) wpart[t >> 6] = sc;
    __syncthreads();
    if (t == 0) { int a = 0; for (int i = 0; i < 4; ++i) { woff[i] = a; a += wpart[i]; } }
    __syncthreads();
    int run = bsum[blockIdx.x] + woff[t >> 6] + (sc - s);
    if (base + 0 < n) { rowptr[base + 0] = run; cursor[base + 0] = run; run += v.x; inv[base + 0] = rsqrtf(fmaxf((float)v.x, 1.0f)); }
    if (base + 1 < n) { rowptr[base + 1] = run; cursor[base + 1] = run; run += v.y; inv[base + 1] = rsqrtf(fmaxf((float)v.y, 1.0f)); }
    if (base + 2 < n) { rowptr[base + 2] = run; cursor[base + 2] = run; run += v.z; inv[base + 2] = rsqrtf(fmaxf((float)v.z, 1.0f)); }
    if (base + 3 < n) { rowptr[base + 3] = run; cursor[base + 3] = run; run += v.w; inv[base + 3] = rsqrtf(fmaxf((float)v.w, 1.0f)); }
}

// ---------------- bucket edges by dst (counting sort fill) ----------------

__global__ void fill_kernel(const int* __restrict__ src, const int* __restrict__ dst,
                            const float* __restrict__ inv, int* __restrict__ cursor,
                            int* __restrict__ src_s, float* __restrict__ norm_s, int E) {
    int e = blockIdx.x * blockDim.x + threadIdx.x;
    if (e >= E) return;
    int s = src[e];
    int d = dst[e];
    int pos = atomicAdd(&cursor[d], 1);
    src_s[pos] = s;
    norm_s[pos] = inv[s] * inv[d];
}

// ---------------- gather aggregation pass: one wave per node, 128 cols/pass ----------------

__global__ void gather_agg_pass(const float* __restrict__ x, int coff, int ss,
                                const int* __restrict__ rowptr, const int* __restrict__ src_s,
                                const float* __restrict__ norm_s,
                                unsigned short* __restrict__ agg_hi,
                                unsigned short* __restrict__ agg_lo, int as) {
    int node = blockIdx.x * 4 + (threadIdx.x >> 6);
    if (node >= N_NODES) return;
    int lane = threadIdx.x & 63;
    int beg = rowptr[node];
    int end = rowptr[node + 1];
    const float* xb = x + coff + (size_t)lane * 2;

    float2 acc = {0.0f, 0.0f};
    int p = beg;
    for (; p + 4 <= end; p += 4) {
        int s0 = src_s[p], s1 = src_s[p + 1], s2 = src_s[p + 2], s3 = src_s[p + 3];
        float n0 = norm_s[p], n1 = norm_s[p + 1], n2 = norm_s[p + 2], n3 = norm_s[p + 3];
        float2 v0 = *(const float2*)(xb + (size_t)s0 * ss);
        float2 v1 = *(const float2*)(xb + (size_t)s1 * ss);
        float2 v2 = *(const float2*)(xb + (size_t)s2 * ss);
        float2 v3 = *(const float2*)(xb + (size_t)s3 * ss);
        acc.x = fmaf(v0.x, n0, acc.x); acc.y = fmaf(v0.y, n0, acc.y);
        acc.x = fmaf(v1.x, n1, acc.x); acc.y = fmaf(v1.y, n1, acc.y);
        acc.x = fmaf(v2.x, n2, acc.x); acc.y = fmaf(v2.y, n2, acc.y);
        acc.x = fmaf(v3.x, n3, acc.x); acc.y = fmaf(v3.y, n3, acc.y);
    }
    for (; p < end; ++p) {
        int s0 = src_s[p];
        float n0 = norm_s[p];
        float2 v0 = *(const float2*)(xb + (size_t)s0 * ss);
        acc.x = fmaf(v0.x, n0, acc.x);
        acc.y = fmaf(v0.y, n0, acc.y);
    }

    unsigned short h0, l0, h1, l1;
    split2(acc.x, h0, l0);
    split2(acc.y, h1, l1);
    unsigned hp = (unsigned)h0 | ((unsigned)h1 << 16);
    unsigned lp = (unsigned)l0 | ((unsigned)l1 << 16);
    size_t o = (size_t)node * as + coff + (size_t)lane * 2;
    *(unsigned*)(agg_hi + o) = hp;
    *(unsigned*)(agg_lo + o) = lp;
}

// ---------------- W split + transpose (both weights in one launch) ----------------

__global__ void split_w_all(const float* __restrict__ W1, const float* __restrict__ W2,
                            unsigned short* __restrict__ w1hi, unsigned short* __restrict__ w1lo,
                            unsigned short* __restrict__ w2hi, unsigned short* __restrict__ w2lo) {
    int i = blockIdx.x * 256 + threadIdx.x;
    if (i < 128 * 256) {
        int k = i >> 8;
        int n = i & 255;
        unsigned short h, l;
        split2(W1[i], h, l);
        w1hi[(size_t)n * 128 + k] = h;
        w1lo[(size_t)n * 128 + k] = l;
    } else {
        int j = i - 128 * 256;
        int k = j >> 8;
        int n = j & 255;
        unsigned short h, l;
        split2(W2[j], h, l);
        w2hi[(size_t)n * 256 + k] = h;
        w2lo[(size_t)n * 256 + k] = l;
    }
}

// ---------------- MFMA GEMM (split bf16, swapped operands), stage-all-A ----------------
// out[M,256] = relu(A[M,K] @ W[K,256] + b). A hi/lo bf16 [M][K], W hi/lo bf16 [256][K].
// Block: 256 thr = 4 waves; block tile 32 rows x 256 cols; wave = 32 x 64 cols.
// ALL of the block's A tile is loaded up front (4-8 independent 16B loads/thread,
// single latency exposure), written to padded LDS, ONE barrier, then a fully
// unrolled MFMA loop with B (L2-hot weights) double-buffered in registers.
// D = mfma(W_frag, A_frag): lane holds out[r = row0+rf*16+(lane&15)]
// [c = col0+cf*16+(lane>>4)*4 + reg] -> contiguous float4 epilogue stores.

template<int K, bool RELU>
__global__ __launch_bounds__(256) void gemm_mfma_kernel(
    const unsigned short* __restrict__ Ahi, const unsigned short* __restrict__ Alo,
    const unsigned short* __restrict__ Bhi, const unsigned short* __restrict__ Blo,
    const float* __restrict__ bias, float* __restrict__ out, int M)
{
    constexpr int NT = K / 32;
    constexpr int ROWS = 32;
    __shared__ unsigned short AsH[NT][ROWS][40];
    __shared__ unsigned short AsL[NT][ROWS][40];

    int tid = threadIdx.x;
    int lane = tid & 63;
    int wave = tid >> 6;
    int row0 = blockIdx.x * ROWS;
    int col0 = wave * 64;
    int lr = lane & 15;
    int lhi = lane >> 4;
    int koff0 = lhi * 8;

    // ---- stage ALL of A: threads 0-127 stage hi, 128-255 stage lo ----
    constexpr int SLOTS = ROWS * K / 8;     // short8 slots per matrix
    constexpr int PER = SLOTS / 128;        // K=256 -> 8, K=128 -> 4
    const unsigned short* Asrc = (tid < 128) ? Ahi : Alo;
    int s = tid & 127;

    short8 rr[PER];
    #pragma unroll
    for (int j = 0; j < PER; ++j) {
        int i = j * 128 + s;
        int row = i / (K / 8);
        int kg = (i % (K / 8)) * 8;
        rr[j] = *(const short8*)(Asrc + (size_t)(row0 + row) * K + kg);
    }
    #pragma unroll
    for (int j = 0; j < PER; ++j) {
        int i = j * 128 + s;
        int row = i / (K / 8);
        int kg = (i % (K / 8)) * 8;
        int c = kg >> 5;
        int o = kg & 31;
        if (tid < 128) *(short8*)&AsH[c][row][o] = rr[j];
        else           *(short8*)&AsL[c][row][o] = rr[j];
    }
    __syncthreads();

    // ---- compute: fully unrolled, B double-buffered in registers ----
    f32x4 acc[4][2];
    #pragma unroll
    for (int i = 0; i < 4; ++i)
        #pragma unroll
        for (int j = 0; j < 2; ++j) acc[i][j] = (f32x4){0.f, 0.f, 0.f, 0.f};

    short8 bh[4], bl[4], bh2[4], bl2[4];
    #pragma unroll
    for (int cf = 0; cf < 4; ++cf) {
        size_t boff = (size_t)(col0 + cf * 16 + lr) * K + koff0;
        bh[cf] = *(const short8*)(Bhi + boff);
        bl[cf] = *(const short8*)(Blo + boff);
    }

    #pragma unroll
    for (int t = 0; t < NT; ++t) {
        if (t + 1 < NT) {
            int ko = (t + 1) * 32 + koff0;
            #pragma unroll
            for (int cf = 0; cf < 4; ++cf) {
                size_t boff = (size_t)(col0 + cf * 16 + lr) * K + ko;
                bh2[cf] = *(const short8*)(Bhi + boff);
                bl2[cf] = *(const short8*)(Blo + boff);
            }
        }
        short8 ah[2], al[2];
        #pragma unroll
        for (int rf = 0; rf < 2; ++rf) {
            ah[rf] = *(const short8*)&AsH[t][rf * 16 + lr][koff0];
            al[rf] = *(const short8*)&AsL[t][rf * 16 + lr][koff0];
        }
        #pragma unroll
        for (int cf = 0; cf < 4; ++cf)
            #pragma unroll
            for (int rf = 0; rf < 2; ++rf) {
                acc[cf][rf] = __builtin_amdgcn_mfma_f32_16x16x32_bf16(bh[cf], ah[rf], acc[cf][rf], 0, 0, 0);
                acc[cf][rf] = __builtin_amdgcn_mfma_f32_16x16x32_bf16(bl[cf], ah[rf], acc[cf][rf], 0, 0, 0);
                acc[cf][rf] = __builtin_amdgcn_mfma_f32_16x16x32_bf16(bh[cf], al[rf], acc[cf][rf], 0, 0, 0);
            }
        if (t + 1 < NT) {
            #pragma unroll
            for (int cf = 0; cf < 4; ++cf) { bh[cf] = bh2[cf]; bl[cf] = bl2[cf]; }
        }
    }

    // epilogue: bias + relu, float4 stores (contiguous cols per lane)
    #pragma unroll
    for (int cf = 0; cf < 4; ++cf) {
        int c = col0 + cf * 16 + lhi * 4;
        float4 bv = *(const float4*)(bias + c);
        #pragma unroll
        for (int rf = 0; rf < 2; ++rf) {
            int r = row0 + rf * 16 + lr;
            if (r < M) {
                float4 v;
                v.x = acc[cf][rf][0] + bv.x;
                v.y = acc[cf][rf][1] + bv.y;
                v.z = acc[cf][rf][2] + bv.z;
                v.w = acc[cf][rf][3] + bv.w;
                if (RELU) {
                    v.x = fmaxf(v.x, 0.f); v.y = fmaxf(v.y, 0.f);
                    v.z = fmaxf(v.z, 0.f); v.w = fmaxf(v.w, 0.f);
                }
                *(float4*)(out + (size_t)r * 256 + c) = v;
            }
        }
    }
}

// ---------------- dense head + softmax, LDS-staged ----------------

__global__ __launch_bounds__(256) void dense_softmax_kernel(const float* __restrict__ h,
                                                            const float* __restrict__ Wd,
                                                            const float* __restrict__ bd,
                                                            float* __restrict__ out, int M) {
    __shared__ float hs[32][260];
    __shared__ float wt[40][260];
    int tid = threadIdx.x;
    int row0 = blockIdx.x * 32;

    for (int i = tid; i < 40 * 256; i += 256) {
        int k = i / 40;
        int c = i - k * 40;
        wt[c][k] = Wd[i];
    }
    #pragma unroll
    for (int i = 0; i < 8; ++i) {
        int f = tid + i * 256;
        int r = f >> 6;
        int k4 = (f & 63) << 2;
        float4 v = make_float4(0.f, 0.f, 0.f, 0.f);
        if (row0 + r < M) v = *(const float4*)(h + (size_t)(row0 + r) * 256 + k4);
        *(float4*)&hs[r][k4] = v;
    }
    __syncthreads();

    int r  = tid >> 3;
    int cg = tid & 7;
    int c0 = cg * 5;

    float acc[5] = {0.f, 0.f, 0.f, 0.f, 0.f};
    #pragma unroll 4
    for (int k4 = 0; k4 < 64; ++k4) {
        float4 hv = *(float4*)&hs[r][k4 * 4];
        #pragma unroll
        for (int j = 0; j < 5; ++j) {
            float4 wv = *(float4*)&wt[c0 + j][k4 * 4];
            acc[j] = fmaf(hv.x, wv.x, acc[j]);
            acc[j] = fmaf(hv.y, wv.y, acc[j]);
            acc[j] = fmaf(hv.z, wv.z, acc[j]);
            acc[j] = fmaf(hv.w, wv.w, acc[j]);
        }
    }
    #pragma unroll
    for (int j = 0; j < 5; ++j) acc[j] += bd[c0 + j];

    float m = acc[0];
    #pragma unroll
    for (int j = 1; j < 5; ++j) m = fmaxf(m, acc[j]);
    #pragma unroll
    for (int off = 1; off < 8; off <<= 1) m = fmaxf(m, __shfl_xor(m, off));

    float e[5], s = 0.f;
    #pragma unroll
    for (int j = 0; j < 5; ++j) { e[j] = expf(acc[j] - m); s += e[j]; }
    #pragma unroll
    for (int off = 1; off < 8; off <<= 1) s += __shfl_xor(s, off);

    int row = row0 + r;
    if (row < M) {
        float inv_s = 1.0f / s;
        float* orow = out + (size_t)row * 40 + c0;
        #pragma unroll
        for (int j = 0; j < 5; ++j) orow[j] = e[j] * inv_s;
    }
}

// ---------------- launch ----------------

extern "C" void kernel_launch(void* const* d_in, const int* in_sizes, int n_in,
                              void* d_out, int out_size, void* d_ws, size_t ws_size,
                              hipStream_t stream) {
    const float* x  = (const float*)d_in[0];
    const int*   ei = (const int*)d_in[1];
    const float* W1 = (const float*)d_in[2];
    const float* b1 = (const float*)d_in[3];
    const float* W2 = (const float*)d_in[4];
    const float* b2 = (const float*)d_in[5];
    const float* Wd = (const float*)d_in[6];
    const float* bd = (const float*)d_in[7];
    float* out = (float*)d_out;

    const int N = N_NODES;
    const int E = in_sizes[1] / 2;
    const int* src = ei;
    const int* dst = ei + E;

    const int MP = 50048;   // M padded to multiple of 32 for MFMA tiles

    // workspace layout (bytes, 1KB-aligned). ~110 MB.
    char* ws = (char*)d_ws;
    size_t off = 0;
    auto alloc = [&](size_t bytes) { char* p = ws + off; off += (bytes + 1023) & ~(size_t)1023; return p; };
    int*   deg    = (int*)alloc((size_t)N * 4);
    float* inv    = (float*)alloc((size_t)N * 4);
    int*   rowptr = (int*)alloc((size_t)(N + 1) * 4);
    int*   cursor = (int*)alloc((size_t)N * 4);
    int*   bsum   = (int*)alloc((size_t)64 * 4);
    int*   src_s  = (int*)alloc((size_t)E * 4);
    float* norm_s = (float*)alloc((size_t)E * 4);
    float* h1     = (float*)alloc((size_t)N * 256 * 4);                    // h1 / h2 (f32)
    unsigned short* aggU = (unsigned short*)alloc((size_t)MP * 256 * 2 * 2); // union region
    unsigned short* w1hi = (unsigned short*)alloc((size_t)128 * 256 * 2);
    unsigned short* w1lo = (unsigned short*)alloc((size_t)128 * 256 * 2);
    unsigned short* w2hi = (unsigned short*)alloc((size_t)256 * 256 * 2);
    unsigned short* w2lo = (unsigned short*)alloc((size_t)256 * 256 * 2);

    // union aliases: agg1 (K=128) uses first half; agg2 (K=256) uses whole region
    unsigned short* agg1_hi = aggU;
    unsigned short* agg1_lo = aggU + (size_t)MP * 128;
    unsigned short* agg2_hi = aggU;
    unsigned short* agg2_lo = aggU + (size_t)MP * 256;
    float* h2 = h1;

    hipMemsetAsync(deg, 0, (size_t)N * 4, stream);

    const int nb = (N + 1023) / 1024;   // 49 scan blocks

    // degree -> scan (rowptr+cursor+inv) -> bucketed (src_s, norm_s)
    deg_kernel<<<(E + 255) / 256, 256, 0, stream>>>(dst, deg, E);
    scan_p1<<<nb, 256, 0, stream>>>(deg, bsum, N);
    scan_p2<<<1, 64, 0, stream>>>(bsum, nb, rowptr, N);
    scan_p3<<<nb, 256, 0, stream>>>(deg, bsum, rowptr, cursor, inv, N);
    fill_kernel<<<(E + 255) / 256, 256, 0, stream>>>(src, dst, inv, cursor, src_s, norm_s, E);

    // pre-split weights (transposed), one launch
    split_w_all<<<(128 * 256 + 256 * 256) / 256, 256, 0, stream>>>(W1, W2, w1hi, w1lo, w2hi, w2lo);

    const int gblocks = (N + 3) / 4;

    // conv1: gather into agg1 (split bf16), then h1 = relu(agg1 @ W1 + b1) via MFMA
    gather_agg_pass<<<gblocks, 256, 0, stream>>>(x, 0, 128, rowptr, src_s, norm_s, agg1_hi, agg1_lo, 128);
    gemm_mfma_kernel<128, true><<<MP / 32, 256, 0, stream>>>(agg1_hi, agg1_lo, w1hi, w1lo, b1, h1, N);

    // conv2: gather h1 into agg2 (split bf16) in two 128-col passes, then MFMA GEMM
    gather_agg_pass<<<gblocks, 256, 0, stream>>>(h1, 0,   256, rowptr, src_s, norm_s, agg2_hi, agg2_lo, 256);
    gather_agg_pass<<<gblocks, 256, 0, stream>>>(h1, 128, 256, rowptr, src_s, norm_s, agg2_hi, agg2_lo, 256);
    gemm_mfma_kernel<256, true><<<MP / 32, 256, 0, stream>>>(agg2_hi, agg2_lo, w2hi, w2lo, b2, h2, N);

    // dense + softmax (LDS-staged)
    dense_softmax_kernel<<<(N + 31) / 32, 256, 0, stream>>>(h2, Wd, bd, out, N);
}

// Round 13
// 314.826 us; speedup vs baseline: 1.2911x; 1.1545x over previous
//
#include <hip/hip_runtime.h>
#include <hip/hip_bf16.h>
#include <math.h>

#define N_NODES 50000

typedef short short8 __attribute__((ext_vector_type(8)));
typedef float f32x4 __attribute__((ext_vector_type(4)));

// RNE split of f32 into bf16 hi + bf16 lo (a ~= hi + lo, rel err ~2^-18)
static __device__ __forceinline__ void split2(float x, unsigned short& hi, unsigned short& lo) {
    unsigned u = __builtin_bit_cast(unsigned, x);
    unsigned r = u + 0x7FFF + ((u >> 16) & 1);
    hi = (unsigned short)(r >> 16);
    float hf = __builtin_bit_cast(float, (unsigned)hi << 16);
    float res = x - hf;
    unsigned v = __builtin_bit_cast(unsigned, res);
    unsigned r2 = v + 0x7FFF + ((v >> 16) & 1);
    lo = (unsigned short)(r2 >> 16);
}

// ---------------- degree (int histogram) ----------------

__global__ void deg_kernel(const int* __restrict__ dst, int* __restrict__ deg, int E) {
    int e = blockIdx.x * blockDim.x + threadIdx.x;
    if (e < E) atomicAdd(&deg[dst[e]], 1);
}

// ---------------- multi-block exclusive scan ----------------

__global__ void scan_p1(const int* __restrict__ deg, int* __restrict__ bsum, int n) {
    int t = threadIdx.x;                    // 256 threads
    int base = blockIdx.x * 1024 + t * 4;
    int4 v = make_int4(0, 0, 0, 0);
    if (base + 3 < n) v = *(const int4*)(deg + base);
    else {
        if (base + 0 < n) v.x = deg[base + 0];
        if (base + 1 < n) v.y = deg[base + 1];
        if (base + 2 < n) v.z = deg[base + 2];
    }
    int s = v.x + v.y + v.z + v.w;
    #pragma unroll
    for (int off = 32; off > 0; off >>= 1) s += __shfl_xor(s, off);
    __shared__ int wpart[4];
    if ((t & 63) == 0) wpart[t >> 6] = s;
    __syncthreads();
    if (t == 0) bsum[blockIdx.x] = wpart[0] + wpart[1] + wpart[2] + wpart[3];
}

__global__ void scan_p2(int* __restrict__ bsum, int nb, int* __restrict__ rowptr, int n) {
    int t = threadIdx.x;                    // 64 threads, nb <= 64
    int v = (t < nb) ? bsum[t] : 0;
    int sc = v;
    #pragma unroll
    for (int off = 1; off < 64; off <<= 1) {
        int u = __shfl_up(sc, off);
        if (t >= off) sc += u;
    }
    if (t < nb) bsum[t] = sc - v;           // exclusive block offsets
    if (t == 63) rowptr[n] = sc;            // grand total
}

// scan_p3 also computes inv_sqrt(deg) (folded kernel)
__global__ void scan_p3(const int* __restrict__ deg, const int* __restrict__ bsum,
                        int* __restrict__ rowptr, int* __restrict__ cursor,
                        float* __restrict__ inv, int n) {
    int t = threadIdx.x;                    // 256 threads
    int base = blockIdx.x * 1024 + t * 4;
    int4 v = make_int4(0, 0, 0, 0);
    if (base + 3 < n) v = *(const int4*)(deg + base);
    else {
        if (base + 0 < n) v.x = deg[base + 0];
        if (base + 1 < n) v.y = deg[base + 1];
        if (base + 2 < n) v.z = deg[base + 2];
    }
    int s = v.x + v.y + v.z + v.w;
    int lane = t & 63;
    int sc = s;
    #pragma unroll
    for (int off = 1; off < 64; off <<= 1) {
        int u = __shfl_up(sc, off);
        if (lane >= off) sc += u;
    }
    __shared__ int wpart[4], woff[4];
    if (lane == 63) wpart[t >> 6] = sc;
    __syncthreads();
    if (t == 0) { int a = 0; for (int i = 0; i < 4; ++i) { woff[i] = a; a += wpart[i]; } }
    __syncthreads();
    int run = bsum[blockIdx.x] + woff[t >> 6] + (sc - s);
    if (base + 0 < n) { rowptr[base + 0] = run; cursor[base + 0] = run; run += v.x; inv[base + 0] = rsqrtf(fmaxf((float)v.x, 1.0f)); }
    if (base + 1 < n) { rowptr[base + 1] = run; cursor[base + 1] = run; run += v.y; inv[base + 1] = rsqrtf(fmaxf((float)v.y, 1.0f)); }
    if (base + 2 < n) { rowptr[base + 2] = run; cursor[base + 2] = run; run += v.z; inv[base + 2] = rsqrtf(fmaxf((float)v.z, 1.0f)); }
    if (base + 3 < n) { rowptr[base + 3] = run; cursor[base + 3] = run; run += v.w; inv[base + 3] = rsqrtf(fmaxf((float)v.w, 1.0f)); }
}

// ---------------- bucket edges by dst (counting sort fill) ----------------

__global__ void fill_kernel(const int* __restrict__ src, const int* __restrict__ dst,
                            const float* __restrict__ inv, int* __restrict__ cursor,
                            int* __restrict__ src_s, float* __restrict__ norm_s, int E) {
    int e = blockIdx.x * blockDim.x + threadIdx.x;
    if (e >= E) return;
    int s = src[e];
    int d = dst[e];
    int pos = atomicAdd(&cursor[d], 1);
    src_s[pos] = s;
    norm_s[pos] = inv[s] * inv[d];
}

// ---------------- gather aggregation pass: one wave per node, 128 cols/pass ----------------

__global__ void gather_agg_pass(const float* __restrict__ x, int coff, int ss,
                                const int* __restrict__ rowptr, const int* __restrict__ src_s,
                                const float* __restrict__ norm_s,
                                unsigned short* __restrict__ agg_hi,
                                unsigned short* __restrict__ agg_lo, int as) {
    int node = blockIdx.x * 4 + (threadIdx.x >> 6);
    if (node >= N_NODES) return;
    int lane = threadIdx.x & 63;
    int beg = rowptr[node];
    int end = rowptr[node + 1];
    const float* xb = x + coff + (size_t)lane * 2;

    float2 acc = {0.0f, 0.0f};
    int p = beg;
    for (; p + 4 <= end; p += 4) {
        int s0 = src_s[p], s1 = src_s[p + 1], s2 = src_s[p + 2], s3 = src_s[p + 3];
        float n0 = norm_s[p], n1 = norm_s[p + 1], n2 = norm_s[p + 2], n3 = norm_s[p + 3];
        float2 v0 = *(const float2*)(xb + (size_t)s0 * ss);
        float2 v1 = *(const float2*)(xb + (size_t)s1 * ss);
        float2 v2 = *(const float2*)(xb + (size_t)s2 * ss);
        float2 v3 = *(const float2*)(xb + (size_t)s3 * ss);
        acc.x = fmaf(v0.x, n0, acc.x); acc.y = fmaf(v0.y, n0, acc.y);
        acc.x = fmaf(v1.x, n1, acc.x); acc.y = fmaf(v1.y, n1, acc.y);
        acc.x = fmaf(v2.x, n2, acc.x); acc.y = fmaf(v2.y, n2, acc.y);
        acc.x = fmaf(v3.x, n3, acc.x); acc.y = fmaf(v3.y, n3, acc.y);
    }
    for (; p < end; ++p) {
        int s0 = src_s[p];
        float n0 = norm_s[p];
        float2 v0 = *(const float2*)(xb + (size_t)s0 * ss);
        acc.x = fmaf(v0.x, n0, acc.x);
        acc.y = fmaf(v0.y, n0, acc.y);
    }

    unsigned short h0, l0, h1, l1;
    split2(acc.x, h0, l0);
    split2(acc.y, h1, l1);
    unsigned hp = (unsigned)h0 | ((unsigned)h1 << 16);
    unsigned lp = (unsigned)l0 | ((unsigned)l1 << 16);
    size_t o = (size_t)node * as + coff + (size_t)lane * 2;
    *(unsigned*)(agg_hi + o) = hp;
    *(unsigned*)(agg_lo + o) = lp;
}

// ---------------- W split + transpose (both weights in one launch) ----------------

__global__ void split_w_all(const float* __restrict__ W1, const float* __restrict__ W2,
                            unsigned short* __restrict__ w1hi, unsigned short* __restrict__ w1lo,
                            unsigned short* __restrict__ w2hi, unsigned short* __restrict__ w2lo) {
    int i = blockIdx.x * 256 + threadIdx.x;
    if (i < 128 * 256) {
        int k = i >> 8;
        int n = i & 255;
        unsigned short h, l;
        split2(W1[i], h, l);
        w1hi[(size_t)n * 128 + k] = h;
        w1lo[(size_t)n * 128 + k] = l;
    } else {
        int j = i - 128 * 256;
        int k = j >> 8;
        int n = j & 255;
        unsigned short h, l;
        split2(W2[j], h, l);
        w2hi[(size_t)n * 256 + k] = h;
        w2lo[(size_t)n * 256 + k] = l;
    }
}

// ---------------- MFMA GEMM (split bf16, swapped operands), 128-row tile ----------------
// out[M,256] = relu(A[M,K] @ W[K,256] + b). A hi/lo bf16 [M][K], W hi/lo bf16 [256][K].
// Block: 256 thr = 4 waves; block tile 128 rows x 256 cols; wave = 128 x 64 cols.
// Per BK=32 chunk/wave: 8 L2 B-loads, then 4 HBM A-prefetch loads (B first so
// MFMA's B-wait leaves A in flight), 16 ds_reads, 96 MFMAs (~480cy) covering both
// latencies. A chunk-double-buffered in padded LDS [2][128][40] hi/lo.
// D = mfma(W_frag, A_frag): lane holds out[r=row0+rfx*16+(lane&15)]
// [c=col0+cf*16+(lane>>4)*4 + reg] -> contiguous float4 stores.

template<int K, bool RELU>
__global__ __launch_bounds__(256, 2) void gemm_mfma_kernel(
    const unsigned short* __restrict__ Ahi, const unsigned short* __restrict__ Alo,
    const unsigned short* __restrict__ Bhi, const unsigned short* __restrict__ Blo,
    const float* __restrict__ bias, float* __restrict__ out, int M)
{
    constexpr int ROWS = 128;
    __shared__ unsigned short AsH[2][ROWS][40];
    __shared__ unsigned short AsL[2][ROWS][40];

    int tid = threadIdx.x;
    int lane = tid & 63;
    int wave = tid >> 6;
    int row0 = blockIdx.x * ROWS;
    int col0 = wave * 64;
    int lr = lane & 15;
    int lhi = lane >> 4;
    int koff0 = lhi * 8;

    // staging: threads 0-127 stage hi, 128-255 stage lo; 4 short8 slots each/chunk
    const unsigned short* Asrc = (tid < 128) ? Ahi : Alo;
    int s = tid & 127;
    int srow0 = s >> 2;                     // 0..31 (slot j adds j*32)
    int skg = (s & 3) << 3;                 // 0,8,16,24

    f32x4 acc[4][8];
    #pragma unroll
    for (int i = 0; i < 4; ++i)
        #pragma unroll
        for (int j = 0; j < 8; ++j) acc[i][j] = (f32x4){0.f, 0.f, 0.f, 0.f};

    short8 rr[4];
    // prologue: stage chunk 0
    #pragma unroll
    for (int j = 0; j < 4; ++j)
        rr[j] = *(const short8*)(Asrc + (size_t)(row0 + j * 32 + srow0) * K + skg);
    #pragma unroll
    for (int j = 0; j < 4; ++j) {
        if (tid < 128) *(short8*)&AsH[0][j * 32 + srow0][skg] = rr[j];
        else           *(short8*)&AsL[0][j * 32 + srow0][skg] = rr[j];
    }
    __syncthreads();

    constexpr int NT = K / 32;
    #pragma unroll 1
    for (int t = 0; t < NT; ++t) {
        int cur = t & 1;
        int ko = t * 32 + koff0;

        // B fragments (L2-hot) — issued FIRST
        short8 bh[4], bl[4];
        #pragma unroll
        for (int cf = 0; cf < 4; ++cf) {
            size_t boff = (size_t)(col0 + cf * 16 + lr) * K + ko;
            bh[cf] = *(const short8*)(Bhi + boff);
            bl[cf] = *(const short8*)(Blo + boff);
        }

        // A prefetch for next chunk (HBM) — stays in flight during MFMA
        if (t + 1 < NT) {
            int kk = (t + 1) * 32;
            #pragma unroll
            for (int j = 0; j < 4; ++j)
                rr[j] = *(const short8*)(Asrc + (size_t)(row0 + j * 32 + srow0) * K + kk + skg);
        }

        // compute in two rf-halves to bound register pressure
        #pragma unroll
        for (int half = 0; half < 2; ++half) {
            short8 ah[4], al[4];
            #pragma unroll
            for (int rf = 0; rf < 4; ++rf) {
                int row = (half * 4 + rf) * 16 + lr;
                ah[rf] = *(const short8*)&AsH[cur][row][koff0];
                al[rf] = *(const short8*)&AsL[cur][row][koff0];
            }
            #pragma unroll
            for (int cf = 0; cf < 4; ++cf)
                #pragma unroll
                for (int rf = 0; rf < 4; ++rf) {
                    int rfx = half * 4 + rf;
                    acc[cf][rfx] = __builtin_amdgcn_mfma_f32_16x16x32_bf16(bh[cf], ah[rf], acc[cf][rfx], 0, 0, 0);
                    acc[cf][rfx] = __builtin_amdgcn_mfma_f32_16x16x32_bf16(bl[cf], ah[rf], acc[cf][rfx], 0, 0, 0);
                    acc[cf][rfx] = __builtin_amdgcn_mfma_f32_16x16x32_bf16(bh[cf], al[rf], acc[cf][rfx], 0, 0, 0);
                }
        }

        if (t + 1 < NT) {
            #pragma unroll
            for (int j = 0; j < 4; ++j) {
                if (tid < 128) *(short8*)&AsH[cur ^ 1][j * 32 + srow0][skg] = rr[j];
                else           *(short8*)&AsL[cur ^ 1][j * 32 + srow0][skg] = rr[j];
            }
        }
        __syncthreads();
    }

    // epilogue: bias + relu, float4 stores (contiguous cols per lane)
    #pragma unroll
    for (int cf = 0; cf < 4; ++cf) {
        int c = col0 + cf * 16 + lhi * 4;
        float4 bv = *(const float4*)(bias + c);
        #pragma unroll
        for (int rfx = 0; rfx < 8; ++rfx) {
            int r = row0 + rfx * 16 + lr;
            if (r < M) {
                float4 v;
                v.x = acc[cf][rfx][0] + bv.x;
                v.y = acc[cf][rfx][1] + bv.y;
                v.z = acc[cf][rfx][2] + bv.z;
                v.w = acc[cf][rfx][3] + bv.w;
                if (RELU) {
                    v.x = fmaxf(v.x, 0.f); v.y = fmaxf(v.y, 0.f);
                    v.z = fmaxf(v.z, 0.f); v.w = fmaxf(v.w, 0.f);
                }
                *(float4*)(out + (size_t)r * 256 + c) = v;
            }
        }
    }
}

// ---------------- dense head + softmax, LDS-staged ----------------

__global__ __launch_bounds__(256) void dense_softmax_kernel(const float* __restrict__ h,
                                                            const float* __restrict__ Wd,
                                                            const float* __restrict__ bd,
                                                            float* __restrict__ out, int M) {
    __shared__ float hs[32][260];
    __shared__ float wt[40][260];
    int tid = threadIdx.x;
    int row0 = blockIdx.x * 32;

    for (int i = tid; i < 40 * 256; i += 256) {
        int k = i / 40;
        int c = i - k * 40;
        wt[c][k] = Wd[i];
    }
    #pragma unroll
    for (int i = 0; i < 8; ++i) {
        int f = tid + i * 256;
        int r = f >> 6;
        int k4 = (f & 63) << 2;
        float4 v = make_float4(0.f, 0.f, 0.f, 0.f);
        if (row0 + r < M) v = *(const float4*)(h + (size_t)(row0 + r) * 256 + k4);
        *(float4*)&hs[r][k4] = v;
    }
    __syncthreads();

    int r  = tid >> 3;
    int cg = tid & 7;
    int c0 = cg * 5;

    float acc[5] = {0.f, 0.f, 0.f, 0.f, 0.f};
    #pragma unroll 4
    for (int k4 = 0; k4 < 64; ++k4) {
        float4 hv = *(float4*)&hs[r][k4 * 4];
        #pragma unroll
        for (int j = 0; j < 5; ++j) {
            float4 wv = *(float4*)&wt[c0 + j][k4 * 4];
            acc[j] = fmaf(hv.x, wv.x, acc[j]);
            acc[j] = fmaf(hv.y, wv.y, acc[j]);
            acc[j] = fmaf(hv.z, wv.z, acc[j]);
            acc[j] = fmaf(hv.w, wv.w, acc[j]);
        }
    }
    #pragma unroll
    for (int j = 0; j < 5; ++j) acc[j] += bd[c0 + j];

    float m = acc[0];
    #pragma unroll
    for (int j = 1; j < 5; ++j) m = fmaxf(m, acc[j]);
    #pragma unroll
    for (int off = 1; off < 8; off <<= 1) m = fmaxf(m, __shfl_xor(m, off));

    float e[5], s = 0.f;
    #pragma unroll
    for (int j = 0; j < 5; ++j) { e[j] = expf(acc[j] - m); s += e[j]; }
    #pragma unroll
    for (int off = 1; off < 8; off <<= 1) s += __shfl_xor(s, off);

    int row = row0 + r;
    if (row < M) {
        float inv_s = 1.0f / s;
        float* orow = out + (size_t)row * 40 + c0;
        #pragma unroll
        for (int j = 0; j < 5; ++j) orow[j] = e[j] * inv_s;
    }
}

// ---------------- launch ----------------

extern "C" void kernel_launch(void* const* d_in, const int* in_sizes, int n_in,
                              void* d_out, int out_size, void* d_ws, size_t ws_size,
                              hipStream_t stream) {
    const float* x  = (const float*)d_in[0];
    const int*   ei = (const int*)d_in[1];
    const float* W1 = (const float*)d_in[2];
    const float* b1 = (const float*)d_in[3];
    const float* W2 = (const float*)d_in[4];
    const float* b2 = (const float*)d_in[5];
    const float* Wd = (const float*)d_in[6];
    const float* bd = (const float*)d_in[7];
    float* out = (float*)d_out;

    const int N = N_NODES;
    const int E = in_sizes[1] / 2;
    const int* src = ei;
    const int* dst = ei + E;

    const int MP = 50048;   // M padded to multiple of 128 for MFMA tiles (128*391)

    // workspace layout (bytes, 1KB-aligned). ~110 MB.
    char* ws = (char*)d_ws;
    size_t off = 0;
    auto alloc = [&](size_t bytes) { char* p = ws + off; off += (bytes + 1023) & ~(size_t)1023; return p; };
    int*   deg    = (int*)alloc((size_t)N * 4);
    float* inv    = (float*)alloc((size_t)N * 4);
    int*   rowptr = (int*)alloc((size_t)(N + 1) * 4);
    int*   cursor = (int*)alloc((size_t)N * 4);
    int*   bsum   = (int*)alloc((size_t)64 * 4);
    int*   src_s  = (int*)alloc((size_t)E * 4);
    float* norm_s = (float*)alloc((size_t)E * 4);
    float* h1     = (float*)alloc((size_t)N * 256 * 4);                    // h1 / h2 (f32)
    unsigned short* aggU = (unsigned short*)alloc((size_t)MP * 256 * 2 * 2); // union region
    unsigned short* w1hi = (unsigned short*)alloc((size_t)128 * 256 * 2);
    unsigned short* w1lo = (unsigned short*)alloc((size_t)128 * 256 * 2);
    unsigned short* w2hi = (unsigned short*)alloc((size_t)256 * 256 * 2);
    unsigned short* w2lo = (unsigned short*)alloc((size_t)256 * 256 * 2);

    // union aliases: agg1 (K=128) uses first half; agg2 (K=256) uses whole region
    unsigned short* agg1_hi = aggU;
    unsigned short* agg1_lo = aggU + (size_t)MP * 128;
    unsigned short* agg2_hi = aggU;
    unsigned short* agg2_lo = aggU + (size_t)MP * 256;
    float* h2 = h1;

    hipMemsetAsync(deg, 0, (size_t)N * 4, stream);

    const int nb = (N + 1023) / 1024;   // 49 scan blocks

    // degree -> scan (rowptr+cursor+inv) -> bucketed (src_s, norm_s)
    deg_kernel<<<(E + 255) / 256, 256, 0, stream>>>(dst, deg, E);
    scan_p1<<<nb, 256, 0, stream>>>(deg, bsum, N);
    scan_p2<<<1, 64, 0, stream>>>(bsum, nb, rowptr, N);
    scan_p3<<<nb, 256, 0, stream>>>(deg, bsum, rowptr, cursor, inv, N);
    fill_kernel<<<(E + 255) / 256, 256, 0, stream>>>(src, dst, inv, cursor, src_s, norm_s, E);

    // pre-split weights (transposed), one launch
    split_w_all<<<(128 * 256 + 256 * 256) / 256, 256, 0, stream>>>(W1, W2, w1hi, w1lo, w2hi, w2lo);

    const int gblocks = (N + 3) / 4;

    // conv1: gather into agg1 (split bf16), then h1 = relu(agg1 @ W1 + b1) via MFMA
    gather_agg_pass<<<gblocks, 256, 0, stream>>>(x, 0, 128, rowptr, src_s, norm_s, agg1_hi, agg1_lo, 128);
    gemm_mfma_kernel<128, true><<<MP / 128, 256, 0, stream>>>(agg1_hi, agg1_lo, w1hi, w1lo, b1, h1, N);

    // conv2: gather h1 into agg2 (split bf16) in two 128-col passes, then MFMA GEMM
    gather_agg_pass<<<gblocks, 256, 0, stream>>>(h1, 0,   256, rowptr, src_s, norm_s, agg2_hi, agg2_lo, 256);
    gather_agg_pass<<<gblocks, 256, 0, stream>>>(h1, 128, 256, rowptr, src_s, norm_s, agg2_hi, agg2_lo, 256);
    gemm_mfma_kernel<256, true><<<MP / 128, 256, 0, stream>>>(agg2_hi, agg2_lo, w2hi, w2lo, b2, h2, N);

    // dense + softmax (LDS-staged)
    dense_softmax_kernel<<<(N + 31) / 32, 256, 0, stream>>>(h2, Wd, bd, out, N);
}

// Round 14
// 306.924 us; speedup vs baseline: 1.3244x; 1.0257x over previous
//
#include <hip/hip_runtime.h>
#include <hip/hip_bf16.h>
#include <math.h>

#define N_NODES 50000

typedef short short8 __attribute__((ext_vector_type(8)));
typedef float f32x4 __attribute__((ext_vector_type(4)));

// RNE split of f32 into bf16 hi + bf16 lo (a ~= hi + lo, rel err ~2^-18)
static __device__ __forceinline__ void split2(float x, unsigned short& hi, unsigned short& lo) {
    unsigned u = __builtin_bit_cast(unsigned, x);
    unsigned r = u + 0x7FFF + ((u >> 16) & 1);
    hi = (unsigned short)(r >> 16);
    float hf = __builtin_bit_cast(float, (unsigned)hi << 16);
    float res = x - hf;
    unsigned v = __builtin_bit_cast(unsigned, res);
    unsigned r2 = v + 0x7FFF + ((v >> 16) & 1);
    lo = (unsigned short)(r2 >> 16);
}

// ---------------- degree (int histogram) ----------------

__global__ void deg_kernel(const int* __restrict__ dst, int* __restrict__ deg, int E) {
    int e = blockIdx.x * blockDim.x + threadIdx.x;
    if (e < E) atomicAdd(&deg[dst[e]], 1);
}

// ---------------- multi-block exclusive scan ----------------

__global__ void scan_p1(const int* __restrict__ deg, int* __restrict__ bsum, int n) {
    int t = threadIdx.x;                    // 256 threads
    int base = blockIdx.x * 1024 + t * 4;
    int4 v = make_int4(0, 0, 0, 0);
    if (base + 3 < n) v = *(const int4*)(deg + base);
    else {
        if (base + 0 < n) v.x = deg[base + 0];
        if (base + 1 < n) v.y = deg[base + 1];
        if (base + 2 < n) v.z = deg[base + 2];
    }
    int s = v.x + v.y + v.z + v.w;
    #pragma unroll
    for (int off = 32; off > 0; off >>= 1) s += __shfl_xor(s, off);
    __shared__ int wpart[4];
    if ((t & 63) == 0) wpart[t >> 6] = s;
    __syncthreads();
    if (t == 0) bsum[blockIdx.x] = wpart[0] + wpart[1] + wpart[2] + wpart[3];
}

__global__ void scan_p2(int* __restrict__ bsum, int nb, int* __restrict__ rowptr, int n) {
    int t = threadIdx.x;                    // 64 threads, nb <= 64
    int v = (t < nb) ? bsum[t] : 0;
    int sc = v;
    #pragma unroll
    for (int off = 1; off < 64; off <<= 1) {
        int u = __shfl_up(sc, off);
        if (t >= off) sc += u;
    }
    if (t < nb) bsum[t] = sc - v;           // exclusive block offsets
    if (t == 63) rowptr[n] = sc;            // grand total
}

// scan_p3 also computes inv_sqrt(deg) (folded kernel)
__global__ void scan_p3(const int* __restrict__ deg, const int* __restrict__ bsum,
                        int* __restrict__ rowptr, int* __restrict__ cursor,
                        float* __restrict__ inv, int n) {
    int t = threadIdx.x;                    // 256 threads
    int base = blockIdx.x * 1024 + t * 4;
    int4 v = make_int4(0, 0, 0, 0);
    if (base + 3 < n) v = *(const int4*)(deg + base);
    else {
        if (base + 0 < n) v.x = deg[base + 0];
        if (base + 1 < n) v.y = deg[base + 1];
        if (base + 2 < n) v.z = deg[base + 2];
    }
    int s = v.x + v.y + v.z + v.w;
    int lane = t & 63;
    int sc = s;
    #pragma unroll
    for (int off = 1; off < 64; off <<= 1) {
        int u = __shfl_up(sc, off);
        if (lane >= off) sc += u;
    }
    __shared__ int wpart[4], woff[4];
    if (lane == 63) wpart[t >> 6] = sc;
    __syncthreads();
    if (t == 0) { int a = 0; for (int i = 0; i < 4; ++i) { woff[i] = a; a += wpart[i]; } }
    __syncthreads();
    int run = bsum[blockIdx.x] + woff[t >> 6] + (sc - s);
    if (base + 0 < n) { rowptr[base + 0] = run; cursor[base + 0] = run; run += v.x; inv[base + 0] = rsqrtf(fmaxf((float)v.x, 1.0f)); }
    if (base + 1 < n) { rowptr[base + 1] = run; cursor[base + 1] = run; run += v.y; inv[base + 1] = rsqrtf(fmaxf((float)v.y, 1.0f)); }
    if (base + 2 < n) { rowptr[base + 2] = run; cursor[base + 2] = run; run += v.z; inv[base + 2] = rsqrtf(fmaxf((float)v.z, 1.0f)); }
    if (base + 3 < n) { rowptr[base + 3] = run; cursor[base + 3] = run; run += v.w; inv[base + 3] = rsqrtf(fmaxf((float)v.w, 1.0f)); }
}

// ---------------- bucket edges by dst (counting sort fill, packed 8B) ----------------

__global__ void fill_kernel(const int* __restrict__ src, const int* __restrict__ dst,
                            const float* __restrict__ inv, int* __restrict__ cursor,
                            int2* __restrict__ edges, int E) {
    int e = blockIdx.x * blockDim.x + threadIdx.x;
    if (e >= E) return;
    int s = src[e];
    int d = dst[e];
    int pos = atomicAdd(&cursor[d], 1);
    float nv = inv[s] * inv[d];
    edges[pos] = make_int2(s, __builtin_bit_cast(int, nv));
}

// ---------------- gather aggregation pass: one wave per node, 128 cols/pass ----------------
// edges packed as (src:int, norm:f32) int2 pairs, read sequentially per bucket.

__global__ void gather_agg_pass(const float* __restrict__ x, int coff, int ss,
                                const int* __restrict__ rowptr, const int2* __restrict__ edges,
                                unsigned short* __restrict__ agg_hi,
                                unsigned short* __restrict__ agg_lo, int as) {
    int node = blockIdx.x * 4 + (threadIdx.x >> 6);
    if (node >= N_NODES) return;
    int lane = threadIdx.x & 63;
    int beg = rowptr[node];
    int end = rowptr[node + 1];
    const float* xb = x + coff + (size_t)lane * 2;

    float2 acc = {0.0f, 0.0f};
    int p = beg;
    for (; p + 4 <= end; p += 4) {
        int2 e0 = edges[p], e1 = edges[p + 1], e2 = edges[p + 2], e3 = edges[p + 3];
        float n0 = __builtin_bit_cast(float, e0.y);
        float n1 = __builtin_bit_cast(float, e1.y);
        float n2 = __builtin_bit_cast(float, e2.y);
        float n3 = __builtin_bit_cast(float, e3.y);
        float2 v0 = *(const float2*)(xb + (size_t)e0.x * ss);
        float2 v1 = *(const float2*)(xb + (size_t)e1.x * ss);
        float2 v2 = *(const float2*)(xb + (size_t)e2.x * ss);
        float2 v3 = *(const float2*)(xb + (size_t)e3.x * ss);
        acc.x = fmaf(v0.x, n0, acc.x); acc.y = fmaf(v0.y, n0, acc.y);
        acc.x = fmaf(v1.x, n1, acc.x); acc.y = fmaf(v1.y, n1, acc.y);
        acc.x = fmaf(v2.x, n2, acc.x); acc.y = fmaf(v2.y, n2, acc.y);
        acc.x = fmaf(v3.x, n3, acc.x); acc.y = fmaf(v3.y, n3, acc.y);
    }
    for (; p < end; ++p) {
        int2 e0 = edges[p];
        float n0 = __builtin_bit_cast(float, e0.y);
        float2 v0 = *(const float2*)(xb + (size_t)e0.x * ss);
        acc.x = fmaf(v0.x, n0, acc.x);
        acc.y = fmaf(v0.y, n0, acc.y);
    }

    unsigned short h0, l0, h1, l1;
    split2(acc.x, h0, l0);
    split2(acc.y, h1, l1);
    unsigned hp = (unsigned)h0 | ((unsigned)h1 << 16);
    unsigned lp = (unsigned)l0 | ((unsigned)l1 << 16);
    size_t o = (size_t)node * as + coff + (size_t)lane * 2;
    *(unsigned*)(agg_hi + o) = hp;
    *(unsigned*)(agg_lo + o) = lp;
}

// ---------------- W split + transpose (both weights in one launch) ----------------

__global__ void split_w_all(const float* __restrict__ W1, const float* __restrict__ W2,
                            unsigned short* __restrict__ w1hi, unsigned short* __restrict__ w1lo,
                            unsigned short* __restrict__ w2hi, unsigned short* __restrict__ w2lo) {
    int i = blockIdx.x * 256 + threadIdx.x;
    if (i < 128 * 256) {
        int k = i >> 8;
        int n = i & 255;
        unsigned short h, l;
        split2(W1[i], h, l);
        w1hi[(size_t)n * 128 + k] = h;
        w1lo[(size_t)n * 128 + k] = l;
    } else {
        int j = i - 128 * 256;
        int k = j >> 8;
        int n = j & 255;
        unsigned short h, l;
        split2(W2[j], h, l);
        w2hi[(size_t)n * 256 + k] = h;
        w2lo[(size_t)n * 256 + k] = l;
    }
}

// ---------------- MFMA GEMM (split bf16, swapped operands), 128-row tile ----------------
// out[M,256] = relu(A[M,K] @ W[K,256] + b). A hi/lo bf16 [M][K], W hi/lo bf16 [256][K].
// Block: 256 thr = 4 waves; block tile 128 rows x 256 cols; wave = 128 x 64 cols.
// Per BK=32 chunk/wave: 8 L2 B-loads, then 4 HBM A-prefetch loads (B first so
// MFMA's B-wait leaves A in flight), 16 ds_reads, 96 MFMAs (~480cy) covering both
// latencies. A chunk-double-buffered in padded LDS [2][128][40] hi/lo.
// D = mfma(W_frag, A_frag): lane holds out[r=row0+rfx*16+(lane&15)]
// [c=col0+cf*16+(lane>>4)*4 + reg] -> contiguous float4 stores.

template<int K, bool RELU>
__global__ __launch_bounds__(256, 2) void gemm_mfma_kernel(
    const unsigned short* __restrict__ Ahi, const unsigned short* __restrict__ Alo,
    const unsigned short* __restrict__ Bhi, const unsigned short* __restrict__ Blo,
    const float* __restrict__ bias, float* __restrict__ out, int M)
{
    constexpr int ROWS = 128;
    __shared__ unsigned short AsH[2][ROWS][40];
    __shared__ unsigned short AsL[2][ROWS][40];

    int tid = threadIdx.x;
    int lane = tid & 63;
    int wave = tid >> 6;
    int row0 = blockIdx.x * ROWS;
    int col0 = wave * 64;
    int lr = lane & 15;
    int lhi = lane >> 4;
    int koff0 = lhi * 8;

    // staging: threads 0-127 stage hi, 128-255 stage lo; 4 short8 slots each/chunk
    const unsigned short* Asrc = (tid < 128) ? Ahi : Alo;
    int s = tid & 127;
    int srow0 = s >> 2;                     // 0..31 (slot j adds j*32)
    int skg = (s & 3) << 3;                 // 0,8,16,24

    f32x4 acc[4][8];
    #pragma unroll
    for (int i = 0; i < 4; ++i)
        #pragma unroll
        for (int j = 0; j < 8; ++j) acc[i][j] = (f32x4){0.f, 0.f, 0.f, 0.f};

    short8 rr[4];
    // prologue: stage chunk 0
    #pragma unroll
    for (int j = 0; j < 4; ++j)
        rr[j] = *(const short8*)(Asrc + (size_t)(row0 + j * 32 + srow0) * K + skg);
    #pragma unroll
    for (int j = 0; j < 4; ++j) {
        if (tid < 128) *(short8*)&AsH[0][j * 32 + srow0][skg] = rr[j];
        else           *(short8*)&AsL[0][j * 32 + srow0][skg] = rr[j];
    }
    __syncthreads();

    constexpr int NT = K / 32;
    #pragma unroll 1
    for (int t = 0; t < NT; ++t) {
        int cur = t & 1;
        int ko = t * 32 + koff0;

        // B fragments (L2-hot) — issued FIRST
        short8 bh[4], bl[4];
        #pragma unroll
        for (int cf = 0; cf < 4; ++cf) {
            size_t boff = (size_t)(col0 + cf * 16 + lr) * K + ko;
            bh[cf] = *(const short8*)(Bhi + boff);
            bl[cf] = *(const short8*)(Blo + boff);
        }

        // A prefetch for next chunk (HBM) — stays in flight during MFMA
        if (t + 1 < NT) {
            int kk = (t + 1) * 32;
            #pragma unroll
            for (int j = 0; j < 4; ++j)
                rr[j] = *(const short8*)(Asrc + (size_t)(row0 + j * 32 + srow0) * K + kk + skg);
        }

        // compute in two rf-halves to bound register pressure
        #pragma unroll
        for (int half = 0; half < 2; ++half) {
            short8 ah[4], al[4];
            #pragma unroll
            for (int rf = 0; rf < 4; ++rf) {
                int row = (half * 4 + rf) * 16 + lr;
                ah[rf] = *(const short8*)&AsH[cur][row][koff0];
                al[rf] = *(const short8*)&AsL[cur][row][koff0];
            }
            #pragma unroll
            for (int cf = 0; cf < 4; ++cf)
                #pragma unroll
                for (int rf = 0; rf < 4; ++rf) {
                    int rfx = half * 4 + rf;
                    acc[cf][rfx] = __builtin_amdgcn_mfma_f32_16x16x32_bf16(bh[cf], ah[rf], acc[cf][rfx], 0, 0, 0);
                    acc[cf][rfx] = __builtin_amdgcn_mfma_f32_16x16x32_bf16(bl[cf], ah[rf], acc[cf][rfx], 0, 0, 0);
                    acc[cf][rfx] = __builtin_amdgcn_mfma_f32_16x16x32_bf16(bh[cf], al[rf], acc[cf][rfx], 0, 0, 0);
                }
        }

        if (t + 1 < NT) {
            #pragma unroll
            for (int j = 0; j < 4; ++j) {
                if (tid < 128) *(short8*)&AsH[cur ^ 1][j * 32 + srow0][skg] = rr[j];
                else           *(short8*)&AsL[cur ^ 1][j * 32 + srow0][skg] = rr[j];
            }
        }
        __syncthreads();
    }

    // epilogue: bias + relu, float4 stores (contiguous cols per lane)
    #pragma unroll
    for (int cf = 0; cf < 4; ++cf) {
        int c = col0 + cf * 16 + lhi * 4;
        float4 bv = *(const float4*)(bias + c);
        #pragma unroll
        for (int rfx = 0; rfx < 8; ++rfx) {
            int r = row0 + rfx * 16 + lr;
            if (r < M) {
                float4 v;
                v.x = acc[cf][rfx][0] + bv.x;
                v.y = acc[cf][rfx][1] + bv.y;
                v.z = acc[cf][rfx][2] + bv.z;
                v.w = acc[cf][rfx][3] + bv.w;
                if (RELU) {
                    v.x = fmaxf(v.x, 0.f); v.y = fmaxf(v.y, 0.f);
                    v.z = fmaxf(v.z, 0.f); v.w = fmaxf(v.w, 0.f);
                }
                *(float4*)(out + (size_t)r * 256 + c) = v;
            }
        }
    }
}

// ---------------- dense head + softmax, LDS-staged ----------------

__global__ __launch_bounds__(256) void dense_softmax_kernel(const float* __restrict__ h,
                                                            const float* __restrict__ Wd,
                                                            const float* __restrict__ bd,
                                                            float* __restrict__ out, int M) {
    __shared__ float hs[32][260];
    __shared__ float wt[40][260];
    int tid = threadIdx.x;
    int row0 = blockIdx.x * 32;

    for (int i = tid; i < 40 * 256; i += 256) {
        int k = i / 40;
        int c = i - k * 40;
        wt[c][k] = Wd[i];
    }
    #pragma unroll
    for (int i = 0; i < 8; ++i) {
        int f = tid + i * 256;
        int r = f >> 6;
        int k4 = (f & 63) << 2;
        float4 v = make_float4(0.f, 0.f, 0.f, 0.f);
        if (row0 + r < M) v = *(const float4*)(h + (size_t)(row0 + r) * 256 + k4);
        *(float4*)&hs[r][k4] = v;
    }
    __syncthreads();

    int r  = tid >> 3;
    int cg = tid & 7;
    int c0 = cg * 5;

    float acc[5] = {0.f, 0.f, 0.f, 0.f, 0.f};
    #pragma unroll 4
    for (int k4 = 0; k4 < 64; ++k4) {
        float4 hv = *(float4*)&hs[r][k4 * 4];
        #pragma unroll
        for (int j = 0; j < 5; ++j) {
            float4 wv = *(float4*)&wt[c0 + j][k4 * 4];
            acc[j] = fmaf(hv.x, wv.x, acc[j]);
            acc[j] = fmaf(hv.y, wv.y, acc[j]);
            acc[j] = fmaf(hv.z, wv.z, acc[j]);
            acc[j] = fmaf(hv.w, wv.w, acc[j]);
        }
    }
    #pragma unroll
    for (int j = 0; j < 5; ++j) acc[j] += bd[c0 + j];

    float m = acc[0];
    #pragma unroll
    for (int j = 1; j < 5; ++j) m = fmaxf(m, acc[j]);
    #pragma unroll
    for (int off = 1; off < 8; off <<= 1) m = fmaxf(m, __shfl_xor(m, off));

    float e[5], s = 0.f;
    #pragma unroll
    for (int j = 0; j < 5; ++j) { e[j] = expf(acc[j] - m); s += e[j]; }
    #pragma unroll
    for (int off = 1; off < 8; off <<= 1) s += __shfl_xor(s, off);

    int row = row0 + r;
    if (row < M) {
        float inv_s = 1.0f / s;
        float* orow = out + (size_t)row * 40 + c0;
        #pragma unroll
        for (int j = 0; j < 5; ++j) orow[j] = e[j] * inv_s;
    }
}

// ---------------- launch ----------------

extern "C" void kernel_launch(void* const* d_in, const int* in_sizes, int n_in,
                              void* d_out, int out_size, void* d_ws, size_t ws_size,
                              hipStream_t stream) {
    const float* x  = (const float*)d_in[0];
    const int*   ei = (const int*)d_in[1];
    const float* W1 = (const float*)d_in[2];
    const float* b1 = (const float*)d_in[3];
    const float* W2 = (const float*)d_in[4];
    const float* b2 = (const float*)d_in[5];
    const float* Wd = (const float*)d_in[6];
    const float* bd = (const float*)d_in[7];
    float* out = (float*)d_out;

    const int N = N_NODES;
    const int E = in_sizes[1] / 2;
    const int* src = ei;
    const int* dst = ei + E;

    const int MP = 50048;   // M padded to multiple of 128 for MFMA tiles (128*391)

    // workspace layout (bytes, 1KB-aligned). ~110 MB.
    char* ws = (char*)d_ws;
    size_t off = 0;
    auto alloc = [&](size_t bytes) { char* p = ws + off; off += (bytes + 1023) & ~(size_t)1023; return p; };
    int*   deg    = (int*)alloc((size_t)N * 4);
    float* inv    = (float*)alloc((size_t)N * 4);
    int*   rowptr = (int*)alloc((size_t)(N + 1) * 4);
    int*   cursor = (int*)alloc((size_t)N * 4);
    int*   bsum   = (int*)alloc((size_t)64 * 4);
    int2*  edges  = (int2*)alloc((size_t)E * 8);
    float* h1     = (float*)alloc((size_t)N * 256 * 4);                    // h1 / h2 (f32)
    unsigned short* aggU = (unsigned short*)alloc((size_t)MP * 256 * 2 * 2); // union region
    unsigned short* w1hi = (unsigned short*)alloc((size_t)128 * 256 * 2);
    unsigned short* w1lo = (unsigned short*)alloc((size_t)128 * 256 * 2);
    unsigned short* w2hi = (unsigned short*)alloc((size_t)256 * 256 * 2);
    unsigned short* w2lo = (unsigned short*)alloc((size_t)256 * 256 * 2);

    // union aliases: agg1 (K=128) uses first half; agg2 (K=256) uses whole region
    unsigned short* agg1_hi = aggU;
    unsigned short* agg1_lo = aggU + (size_t)MP * 128;
    unsigned short* agg2_hi = aggU;
    unsigned short* agg2_lo = aggU + (size_t)MP * 256;
    float* h2 = h1;

    hipMemsetAsync(deg, 0, (size_t)N * 4, stream);

    const int nb = (N + 1023) / 1024;   // 49 scan blocks

    // degree -> scan (rowptr+cursor+inv) -> bucketed packed edges
    deg_kernel<<<(E + 255) / 256, 256, 0, stream>>>(dst, deg, E);
    scan_p1<<<nb, 256, 0, stream>>>(deg, bsum, N);
    scan_p2<<<1, 64, 0, stream>>>(bsum, nb, rowptr, N);
    scan_p3<<<nb, 256, 0, stream>>>(deg, bsum, rowptr, cursor, inv, N);
    fill_kernel<<<(E + 255) / 256, 256, 0, stream>>>(src, dst, inv, cursor, edges, E);

    // pre-split weights (transposed), one launch
    split_w_all<<<(128 * 256 + 256 * 256) / 256, 256, 0, stream>>>(W1, W2, w1hi, w1lo, w2hi, w2lo);

    const int gblocks = (N + 3) / 4;

    // conv1: gather into agg1 (split bf16), then h1 = relu(agg1 @ W1 + b1) via MFMA
    gather_agg_pass<<<gblocks, 256, 0, stream>>>(x, 0, 128, rowptr, edges, agg1_hi, agg1_lo, 128);
    gemm_mfma_kernel<128, true><<<MP / 128, 256, 0, stream>>>(agg1_hi, agg1_lo, w1hi, w1lo, b1, h1, N);

    // conv2: gather h1 into agg2 (split bf16) in two 128-col passes, then MFMA GEMM
    gather_agg_pass<<<gblocks, 256, 0, stream>>>(h1, 0,   256, rowptr, edges, agg2_hi, agg2_lo, 256);
    gather_agg_pass<<<gblocks, 256, 0, stream>>>(h1, 128, 256, rowptr, edges, agg2_hi, agg2_lo, 256);
    gemm_mfma_kernel<256, true><<<MP / 128, 256, 0, stream>>>(agg2_hi, agg2_lo, w2hi, w2lo, b2, h2, N);

    // dense + softmax (LDS-staged)
    dense_softmax_kernel<<<(N + 31) / 32, 256, 0, stream>>>(h2, Wd, bd, out, N);
}